// Round 15
// baseline (263.885 us; speedup 1.0000x reference)
//
#include <hip/hip_runtime.h>
#include <hip/hip_bf16.h>
#include <cstdint>

typedef __bf16 bf16x8 __attribute__((ext_vector_type(8)));
typedef float  f32x4  __attribute__((ext_vector_type(4)));
typedef unsigned short u16x8 __attribute__((ext_vector_type(8)));

__device__ __forceinline__ unsigned short f2bf(float f) {
  __hip_bfloat16 h = __float2bfloat16(f);
  return __builtin_bit_cast(unsigned short, h);
}
__device__ __forceinline__ float bf2f(unsigned short u) {
  return __builtin_bit_cast(float, (unsigned)u << 16);
}

#define GL2LDS16(gp, lp)                                                      \
  __builtin_amdgcn_global_load_lds(                                           \
      (const __attribute__((address_space(1))) unsigned int*)(gp),            \
      (__attribute__((address_space(3))) unsigned int*)(lp), 16, 0, 0)

#define SBAR                                                                  \
  {                                                                           \
    __builtin_amdgcn_s_barrier();                                             \
    __builtin_amdgcn_sched_barrier(0);                                        \
  }
#define WAITV(n)                                                              \
  {                                                                           \
    asm volatile("s_waitcnt vmcnt(" #n ")" ::: "memory");                     \
    __builtin_amdgcn_sched_barrier(0);                                        \
  }
#define WAITL0                                                                \
  {                                                                           \
    asm volatile("s_waitcnt lgkmcnt(0)" ::: "memory");                        \
    __builtin_amdgcn_sched_barrier(0);                                        \
  }

// ===== Merged projection kernel (R14-verified, unchanged): Qp AND KV-proj
// in one 768-block launch. Core = 256x256 tile, 16 waves, per-wave 64x64,
// BK=32, 3-slot 96KB ring, launch_bounds(1024,4) -> 64 VGPR ((1024,8)
// forces 32 VGPR + catastrophic spill, R10 - never again).
// Loop: {stage(t+2); 8 ds_read(t); lgkm0; 16 MFMA; vmcnt(2); s_barrier}.
// Swizzle phys = l ^ (((l>>7)&3)<<4) on BOTH pre-swizzled global source and
// ds_read address (involution; 0 bank conflicts measured).
__global__ __launch_bounds__(1024, 4) void proj_fused(
    const unsigned short* __restrict__ xb, const unsigned short* __restrict__ WT,
    unsigned short* __restrict__ QpO, unsigned short* __restrict__ KVbO,
    const float* __restrict__ bq, const float* __restrict__ bk,
    const float* __restrict__ bv) {
  __shared__ __attribute__((aligned(16))) char lds[3 * 32768];
  const int t = threadIdx.x;
  const int wave = t >> 6, lane = t & 63;
  const int wm = wave >> 2, wn = wave & 3;
  const int fr = lane & 15, fq = lane >> 4;

  const int h = blockIdx.x;
  const bool kv = (h < 512);
  const unsigned short* A;
  const unsigned short* B;
  unsigned short* Cc;
  long long ldc;
  int m0, n0;
  if (kv) {
    const int f = (h & 7) * 64 + (h >> 3);  // bijective XCD chunk over 512
    const int bx = f >> 3, by = f & 7;      // col-major: A (4MB) L2-resident
    m0 = by * 256;
    n0 = bx * 256;
    A = WT + 1024 * 1024;  // [WkT;WvT] rows 0..2047
    B = xb;
    Cc = KVbO;
    ldc = 16384;
  } else {
    const int hh = h - 512;
    const int f = (hh & 7) * 32 + (hh >> 3);  // chunk over 256
    const int bx = f & 3, by = f >> 2;
    m0 = by * 256;
    n0 = bx * 256;
    A = xb;
    B = WT;
    Cc = QpO;
    ldc = 1024;
  }

  const unsigned short* gA;
  const unsigned short* gB;
  {
    int d = t * 16;
    int l = d ^ (((d >> 7) & 3) << 4);
    int row = l >> 6, kel = (l & 63) >> 1;
    gA = A + (long long)(m0 + row) * 1024 + kel;
    gB = B + (long long)(n0 + row) * 1024 + kel;
  }

  const int slotx = (fr >> 1) & 3;
  const int acore = wm * 4096 + fr * 64 + ((fq ^ slotx) << 4);
  const int bcore = 16384 + wn * 4096 + fr * 64 + ((fq ^ slotx) << 4);

  f32x4 acc[4][4];
#pragma unroll
  for (int i = 0; i < 4; ++i)
#pragma unroll
    for (int j = 0; j < 4; ++j) acc[i][j] = (f32x4){0.f, 0.f, 0.f, 0.f};

  const int NT = 32;  // K=1024, BK=32

  auto stage = [&](int tile) {
    char* sb = lds + (tile % 3) * 32768 + wave * 1024;
    const int k0 = tile << 5;
    GL2LDS16(gA + k0, sb);
    GL2LDS16(gB + k0, sb + 16384);
  };

  stage(0);
  stage(1);
  WAITV(2);
  SBAR;

  bf16x8 av[4], bv4[4];
  for (int tt = 0; tt < NT - 2; ++tt) {
    const char* sb = lds + (tt % 3) * 32768;
    stage(tt + 2);
#pragma unroll
    for (int i = 0; i < 4; ++i) {
      av[i] = *(const bf16x8*)(sb + acore + i * 1024);
      bv4[i] = *(const bf16x8*)(sb + bcore + i * 1024);
    }
    WAITL0;
    __builtin_amdgcn_s_setprio(1);
#pragma unroll
    for (int mi = 0; mi < 4; ++mi)
#pragma unroll
      for (int ni = 0; ni < 4; ++ni)
        acc[mi][ni] = __builtin_amdgcn_mfma_f32_16x16x32_bf16(
            av[mi], bv4[ni], acc[mi][ni], 0, 0, 0);
    __builtin_amdgcn_s_setprio(0);
    WAITV(2);
    SBAR;
  }
  {
    const char* sb = lds + ((NT - 2) % 3) * 32768;
#pragma unroll
    for (int i = 0; i < 4; ++i) {
      av[i] = *(const bf16x8*)(sb + acore + i * 1024);
      bv4[i] = *(const bf16x8*)(sb + bcore + i * 1024);
    }
    WAITL0;
#pragma unroll
    for (int mi = 0; mi < 4; ++mi)
#pragma unroll
      for (int ni = 0; ni < 4; ++ni)
        acc[mi][ni] = __builtin_amdgcn_mfma_f32_16x16x32_bf16(
            av[mi], bv4[ni], acc[mi][ni], 0, 0, 0);
    WAITV(0);
    SBAR;
  }
  {
    const char* sb = lds + ((NT - 1) % 3) * 32768;
#pragma unroll
    for (int i = 0; i < 4; ++i) {
      av[i] = *(const bf16x8*)(sb + acore + i * 1024);
      bv4[i] = *(const bf16x8*)(sb + bcore + i * 1024);
    }
    WAITL0;
#pragma unroll
    for (int mi = 0; mi < 4; ++mi)
#pragma unroll
      for (int ni = 0; ni < 4; ++ni)
        acc[mi][ni] = __builtin_amdgcn_mfma_f32_16x16x32_bf16(
            av[mi], bv4[ni], acc[mi][ni], 0, 0, 0);
  }

  // epilogue. C/D: col = lane&15, row = (lane>>4)*4 + j [m89]
  const bool lower = (m0 < 1024);  // KV role: KpT half vs VT half
#pragma unroll
  for (int mi = 0; mi < 4; ++mi) {
    const int rbase = m0 + wm * 64 + mi * 16 + fq * 4;
    float rb[4];
#pragma unroll
    for (int j = 0; j < 4; ++j)
      if (kv) rb[j] = lower ? bk[rbase + j] : bv[rbase - 1024 + j];
#pragma unroll
    for (int ni = 0; ni < 4; ++ni) {
      const int c = n0 + wn * 64 + ni * 16 + fr;
      const float cb = kv ? 0.f : bq[c];
#pragma unroll
      for (int j = 0; j < 4; ++j) {
        float v = acc[mi][ni][j];
        v += kv ? rb[j] : cb;
        if (!kv || lower) v = (v > 0.f) ? v + 1.f : __expf(v);
        Cc[(long long)(rbase + j) * ldc + c] = f2bf(v);
      }
    }
  }
}

// ===== split-K KVt partials + fused ksum (R15): grid (4,4,17).
// z<16: R13-core split-K GEMM (unchanged). z==16: ksum rides along — it is
// independent of splitk (both only READ KVb), so it overlaps instead of a
// serial 1024-block launch.
__global__ __launch_bounds__(1024, 4) void splitk_ksum(
    const unsigned short* __restrict__ A, const unsigned short* __restrict__ B,
    unsigned short* __restrict__ C, float* __restrict__ Ksum) {
  __shared__ __attribute__((aligned(16))) char lds[3 * 32768];
  const int t = threadIdx.x;
  const int wave = t >> 6, lane = t & 63;

  if (blockIdx.z == 16) {
    // ksum: K_sum[b][d] = sum_n KpT[d][b*4096+n]; 16 blocks x 16 waves,
    // 16 rows per wave (same per-row math/order as the old ksum_kernel).
    const int wtask = (blockIdx.y * 4 + blockIdx.x) * 16 + wave;  // 0..255
#pragma unroll
    for (int rr = 0; rr < 16; ++rr) {
      const int gw = wtask * 16 + rr;  // 0..4095
      const int d = gw >> 2, b = gw & 3;
      const unsigned short* p = B + (long long)d * 16384 + b * 4096 + lane * 8;
      float s = 0.f;
#pragma unroll
      for (int it = 0; it < 8; ++it) {
        u16x8 v = *(const u16x8*)(p + it * 512);
#pragma unroll
        for (int j = 0; j < 8; ++j) s += bf2f(v[j]);
      }
#pragma unroll
      for (int o = 32; o > 0; o >>= 1) s += __shfl_down(s, o, 64);
      if (lane == 0) Ksum[b * 1024 + d] = s;
    }
    return;
  }

  const int wm = wave >> 2, wn = wave & 3;
  const int fr = lane & 15, fq = lane >> 4;

  const int gx = gridDim.x, gy = gridDim.y;
  int flat = blockIdx.y * gx + blockIdx.x;
  const int total = gx * gy;
  if ((total & 7) == 0) flat = (flat & 7) * (total >> 3) + (flat >> 3);
  const int bx = flat % gx, by = flat / gx;
  const int m0 = by * 256, n0 = bx * 256;

  const long long z = blockIdx.z;
  const long long koff = (z & 3) * 4096 + (z >> 2) * 1024;
  const unsigned short* Az = A + koff;
  const unsigned short* Bz = B + koff;

  const unsigned short* gA;
  const unsigned short* gB;
  {
    int d = t * 16;
    int l = d ^ (((d >> 7) & 3) << 4);
    int row = l >> 6, kel = (l & 63) >> 1;
    gA = Az + (long long)(m0 + row) * 16384 + kel;
    gB = Bz + (long long)(n0 + row) * 16384 + kel;
  }

  const int slotx = (fr >> 1) & 3;
  const int acore = wm * 4096 + fr * 64 + ((fq ^ slotx) << 4);
  const int bcore = 16384 + wn * 4096 + fr * 64 + ((fq ^ slotx) << 4);

  f32x4 acc[4][4];
#pragma unroll
  for (int i = 0; i < 4; ++i)
#pragma unroll
    for (int j = 0; j < 4; ++j) acc[i][j] = (f32x4){0.f, 0.f, 0.f, 0.f};

  const int NT = 32;

  auto stage = [&](int tile) {
    char* sb = lds + (tile % 3) * 32768 + wave * 1024;
    const int k0 = tile << 5;
    GL2LDS16(gA + k0, sb);
    GL2LDS16(gB + k0, sb + 16384);
  };

  stage(0);
  stage(1);
  WAITV(2);
  SBAR;

  bf16x8 av[4], bv[4];
  for (int tt = 0; tt < NT - 2; ++tt) {
    const char* sb = lds + (tt % 3) * 32768;
    stage(tt + 2);
#pragma unroll
    for (int i = 0; i < 4; ++i) {
      av[i] = *(const bf16x8*)(sb + acore + i * 1024);
      bv[i] = *(const bf16x8*)(sb + bcore + i * 1024);
    }
    WAITL0;
    __builtin_amdgcn_s_setprio(1);
#pragma unroll
    for (int mi = 0; mi < 4; ++mi)
#pragma unroll
      for (int ni = 0; ni < 4; ++ni)
        acc[mi][ni] = __builtin_amdgcn_mfma_f32_16x16x32_bf16(
            av[mi], bv[ni], acc[mi][ni], 0, 0, 0);
    __builtin_amdgcn_s_setprio(0);
    WAITV(2);
    SBAR;
  }
  {
    const char* sb = lds + ((NT - 2) % 3) * 32768;
#pragma unroll
    for (int i = 0; i < 4; ++i) {
      av[i] = *(const bf16x8*)(sb + acore + i * 1024);
      bv[i] = *(const bf16x8*)(sb + bcore + i * 1024);
    }
    WAITL0;
#pragma unroll
    for (int mi = 0; mi < 4; ++mi)
#pragma unroll
      for (int ni = 0; ni < 4; ++ni)
        acc[mi][ni] = __builtin_amdgcn_mfma_f32_16x16x32_bf16(
            av[mi], bv[ni], acc[mi][ni], 0, 0, 0);
    WAITV(0);
    SBAR;
  }
  {
    const char* sb = lds + ((NT - 1) % 3) * 32768;
#pragma unroll
    for (int i = 0; i < 4; ++i) {
      av[i] = *(const bf16x8*)(sb + acore + i * 1024);
      bv[i] = *(const bf16x8*)(sb + bcore + i * 1024);
    }
    WAITL0;
#pragma unroll
    for (int mi = 0; mi < 4; ++mi)
#pragma unroll
      for (int ni = 0; ni < 4; ++ni)
        acc[mi][ni] = __builtin_amdgcn_mfma_f32_16x16x32_bf16(
            av[mi], bv[ni], acc[mi][ni], 0, 0, 0);
  }

  unsigned short* Cu = C + blockIdx.z * 1048576ll;
#pragma unroll
  for (int mi = 0; mi < 4; ++mi) {
    const int rbase = m0 + wm * 64 + mi * 16 + fq * 4;
#pragma unroll
    for (int ni = 0; ni < 4; ++ni) {
      const int c = n0 + wn * 64 + ni * 16 + fr;
#pragma unroll
      for (int j = 0; j < 4; ++j)
        Cu[(long long)(rbase + j) * 1024 + c] = f2bf(acc[mi][ni][j]);
    }
  }
}

// ===== numerator (R13 8-wave BK=64 4-phase core) + FUSED norm (R15):
// each block computes its 256 rows' nrm into LDS (snrm, same per-row
// reduction order as the old norm_kernel -> identical values; 4x
// bx-redundant but removes the norm launch + its serialization).
__global__ __launch_bounds__(512, 2) void gemm_num(
    const unsigned short* __restrict__ A, long long aOffZ,
    const unsigned short* __restrict__ B, long long bOffZ,
    float* __restrict__ C, long long cOffZ,
    const float* __restrict__ Ksum) {
  const long long lda = 1024, ldb = 1024, ldc = 1024;
  const int K = 1024;
  __shared__ __attribute__((aligned(16))) char lds[2 * 65536];
  __shared__ float snrm[256];
  const int t = threadIdx.x;
  const int wave = t >> 6, lane = t & 63;
  const int wm = wave >> 2, wn = wave & 3;
  const int fr = lane & 15, fq = lane >> 4;

  const int gx = gridDim.x, gy = gridDim.y;
  int flat = blockIdx.y * gx + blockIdx.x;
  const int total = gx * gy;
  if ((total & 7) == 0) flat = (flat & 7) * (total >> 3) + (flat >> 3);
  const int bx = flat % gx, by = flat / gx;
  const int m0 = by * 256, n0 = bx * 256;

  const long long z = blockIdx.z;
  const unsigned short* Az = A + z * aOffZ;
  const unsigned short* Bz = B + z * bOffZ;

  // ---- fused norm: nrm[r] = eps + sum_d Qp[m0+r][d]*Ksum[z][d], wave/row
  {
    const float* ks = Ksum + z * 1024 + lane * 8;
    const float4 k0a = *(const float4*)(ks);
    const float4 k1a = *(const float4*)(ks + 4);
    const float4 k0b = *(const float4*)(ks + 512);
    const float4 k1b = *(const float4*)(ks + 516);
    for (int r = wave; r < 256; r += 8) {
      const unsigned short* q = Az + (long long)(m0 + r) * 1024 + lane * 8;
      u16x8 v0 = *(const u16x8*)(q);
      u16x8 v1 = *(const u16x8*)(q + 512);
      float s = bf2f(v0[0]) * k0a.x + bf2f(v0[1]) * k0a.y +
                bf2f(v0[2]) * k0a.z + bf2f(v0[3]) * k0a.w +
                bf2f(v0[4]) * k1a.x + bf2f(v0[5]) * k1a.y +
                bf2f(v0[6]) * k1a.z + bf2f(v0[7]) * k1a.w;
      s += bf2f(v1[0]) * k0b.x + bf2f(v1[1]) * k0b.y + bf2f(v1[2]) * k0b.z +
           bf2f(v1[3]) * k0b.w + bf2f(v1[4]) * k1b.x + bf2f(v1[5]) * k1b.y +
           bf2f(v1[6]) * k1b.z + bf2f(v1[7]) * k1b.w;
#pragma unroll
      for (int o = 32; o > 0; o >>= 1) s += __shfl_down(s, o, 64);
      if (lane == 0) snrm[r] = s + 1e-6f;
    }
  }

  const unsigned short* gA[2];
  const unsigned short* gB[2];
#pragma unroll
  for (int c = 0; c < 2; ++c) {
    int d = c * 8192 + t * 16;
    int l = d ^ (((d >> 7) & 3) << 4);
    int row = l >> 6, kel = (l & 63) >> 1;
    gA[c] = Az + (long long)(m0 + row) * lda + kel;
    gB[c] = Bz + (long long)(n0 + row) * ldb + kel;
  }

  const int slotx = (fr >> 1) & 3;
  const int acore = wm * 8192 + fr * 64 + ((fq ^ slotx) << 4);
  const int bcore = wn * 4096 + fr * 64 + ((fq ^ slotx) << 4);

  f32x4 acc[8][4];
#pragma unroll
  for (int i = 0; i < 8; ++i)
#pragma unroll
    for (int j = 0; j < 4; ++j) acc[i][j] = (f32x4){0.f, 0.f, 0.f, 0.f};

  const int NT = K >> 6;

  auto stage_sub = [&](int tile, int which) {
    char* dst = lds + (tile & 1) * 65536 + which * 16384 + wave * 1024;
    const int kofs = (tile << 6) + ((which >> 1) << 5);
    if (which & 1) {
      GL2LDS16(gB[0] + kofs, dst);
      GL2LDS16(gB[1] + kofs, dst + 8192);
    } else {
      GL2LDS16(gA[0] + kofs, dst);
      GL2LDS16(gA[1] + kofs, dst + 8192);
    }
  };

  stage_sub(0, 0);
  stage_sub(0, 1);
  stage_sub(0, 2);
  stage_sub(0, 3);
  WAITV(4);
  SBAR;

  bf16x8 av[4], bv0[4], bv1[4];
  for (int tt = 0; tt < NT - 1; ++tt) {
    const char* bufp = lds + (tt & 1) * 65536;
#pragma unroll
    for (int i = 0; i < 4; ++i) {
      av[i] = *(const bf16x8*)(bufp + acore + i * 1024);
      bv0[i] = *(const bf16x8*)(bufp + 16384 + bcore + i * 1024);
    }
    stage_sub(tt + 1, 0);
    SBAR;
    WAITL0;
    __builtin_amdgcn_s_setprio(1);
#pragma unroll
    for (int mi = 0; mi < 4; ++mi)
#pragma unroll
      for (int ni = 0; ni < 4; ++ni)
        acc[mi][ni] = __builtin_amdgcn_mfma_f32_16x16x32_bf16(
            av[mi], bv0[ni], acc[mi][ni], 0, 0, 0);
    __builtin_amdgcn_s_setprio(0);
    SBAR;
#pragma unroll
    for (int i = 0; i < 4; ++i)
      av[i] = *(const bf16x8*)(bufp + acore + (4 + i) * 1024);
    stage_sub(tt + 1, 1);
    SBAR;
    WAITL0;
    __builtin_amdgcn_s_setprio(1);
#pragma unroll
    for (int mi = 0; mi < 4; ++mi)
#pragma unroll
      for (int ni = 0; ni < 4; ++ni)
        acc[4 + mi][ni] = __builtin_amdgcn_mfma_f32_16x16x32_bf16(
            av[mi], bv0[ni], acc[4 + mi][ni], 0, 0, 0);
    __builtin_amdgcn_s_setprio(0);
    WAITV(4);
    SBAR;
#pragma unroll
    for (int i = 0; i < 4; ++i) {
      av[i] = *(const bf16x8*)(bufp + 32768 + acore + i * 1024);
      bv1[i] = *(const bf16x8*)(bufp + 49152 + bcore + i * 1024);
    }
    stage_sub(tt + 1, 2);
    SBAR;
    WAITL0;
    __builtin_amdgcn_s_setprio(1);
#pragma unroll
    for (int mi = 0; mi < 4; ++mi)
#pragma unroll
      for (int ni = 0; ni < 4; ++ni)
        acc[mi][ni] = __builtin_amdgcn_mfma_f32_16x16x32_bf16(
            av[mi], bv1[ni], acc[mi][ni], 0, 0, 0);
    __builtin_amdgcn_s_setprio(0);
    SBAR;
#pragma unroll
    for (int i = 0; i < 4; ++i)
      av[i] = *(const bf16x8*)(bufp + 32768 + acore + (4 + i) * 1024);
    stage_sub(tt + 1, 3);
    SBAR;
    WAITL0;
    __builtin_amdgcn_s_setprio(1);
#pragma unroll
    for (int mi = 0; mi < 4; ++mi)
#pragma unroll
      for (int ni = 0; ni < 4; ++ni)
        acc[4 + mi][ni] = __builtin_amdgcn_mfma_f32_16x16x32_bf16(
            av[mi], bv1[ni], acc[4 + mi][ni], 0, 0, 0);
    __builtin_amdgcn_s_setprio(0);
    WAITV(4);
    SBAR;
  }
  {
    const char* bufp = lds + ((NT - 1) & 1) * 65536;
#pragma unroll
    for (int i = 0; i < 4; ++i) {
      av[i] = *(const bf16x8*)(bufp + acore + i * 1024);
      bv0[i] = *(const bf16x8*)(bufp + 16384 + bcore + i * 1024);
    }
    SBAR;
    WAITL0;
#pragma unroll
    for (int mi = 0; mi < 4; ++mi)
#pragma unroll
      for (int ni = 0; ni < 4; ++ni)
        acc[mi][ni] = __builtin_amdgcn_mfma_f32_16x16x32_bf16(
            av[mi], bv0[ni], acc[mi][ni], 0, 0, 0);
    SBAR;
#pragma unroll
    for (int i = 0; i < 4; ++i)
      av[i] = *(const bf16x8*)(bufp + acore + (4 + i) * 1024);
    SBAR;
    WAITL0;
#pragma unroll
    for (int mi = 0; mi < 4; ++mi)
#pragma unroll
      for (int ni = 0; ni < 4; ++ni)
        acc[4 + mi][ni] = __builtin_amdgcn_mfma_f32_16x16x32_bf16(
            av[mi], bv0[ni], acc[4 + mi][ni], 0, 0, 0);
    WAITV(0);
    SBAR;
#pragma unroll
    for (int i = 0; i < 4; ++i) {
      av[i] = *(const bf16x8*)(bufp + 32768 + acore + i * 1024);
      bv1[i] = *(const bf16x8*)(bufp + 49152 + bcore + i * 1024);
    }
    WAITL0;
#pragma unroll
    for (int mi = 0; mi < 4; ++mi)
#pragma unroll
      for (int ni = 0; ni < 4; ++ni)
        acc[mi][ni] = __builtin_amdgcn_mfma_f32_16x16x32_bf16(
            av[mi], bv1[ni], acc[mi][ni], 0, 0, 0);
#pragma unroll
    for (int i = 0; i < 4; ++i)
      av[i] = *(const bf16x8*)(bufp + 32768 + acore + (4 + i) * 1024);
    WAITL0;
#pragma unroll
    for (int mi = 0; mi < 4; ++mi)
#pragma unroll
      for (int ni = 0; ni < 4; ++ni)
        acc[4 + mi][ni] = __builtin_amdgcn_mfma_f32_16x16x32_bf16(
            av[mi], bv1[ni], acc[4 + mi][ni], 0, 0, 0);
  }

  float* Cf = C + z * cOffZ;
#pragma unroll
  for (int mi = 0; mi < 8; ++mi) {
    const int rbase = m0 + wm * 128 + mi * 16 + fq * 4;
    const int rloc = wm * 128 + mi * 16 + fq * 4;
    float nv[4];
#pragma unroll
    for (int j = 0; j < 4; ++j) nv[j] = snrm[rloc + j];
#pragma unroll
    for (int ni = 0; ni < 4; ++ni) {
      const int c = n0 + wn * 64 + ni * 16 + fr;
#pragma unroll
      for (int j = 0; j < 4; ++j)
        Cf[(long long)(rbase + j) * ldc + c] = acc[mi][ni][j] / nv[j];
    }
  }
}

// ===== prep: 3x W-transpose + x->bf16 convert in one launch (z in 0..3) ===
__global__ __launch_bounds__(256) void prep_fused(
    const float* __restrict__ Wq, const float* __restrict__ Wk,
    const float* __restrict__ Wv, unsigned short* __restrict__ WT,
    const float4* __restrict__ x4, uint2* __restrict__ xb4) {
  __shared__ float tile[32][33];
  if (blockIdx.z < 3) {
    const float* W = blockIdx.z == 0 ? Wq : (blockIdx.z == 1 ? Wk : Wv);
    unsigned short* out = WT + (size_t)blockIdx.z * 1024 * 1024;
    const int tx = threadIdx.x & 31, ty = threadIdx.x >> 5;
    const int i0 = blockIdx.y * 32, o0 = blockIdx.x * 32;
#pragma unroll
    for (int s = 0; s < 32; s += 8)
      tile[ty + s][tx] = W[(long long)(i0 + ty + s) * 1024 + o0 + tx];
    __syncthreads();
#pragma unroll
    for (int s = 0; s < 32; s += 8)
      out[(long long)(o0 + ty + s) * 1024 + i0 + tx] = f2bf(tile[tx][ty + s]);
  } else {
    const int flat = blockIdx.y * 32 + blockIdx.x;  // 0..1023
    const int n4 = 4194304;                          // 16384*1024/4
    for (int i = flat * 256 + threadIdx.x; i < n4; i += 1024 * 256) {
      float4 v = x4[i];
      uint2 o;
      o.x = (unsigned)f2bf(v.x) | ((unsigned)f2bf(v.y) << 16);
      o.y = (unsigned)f2bf(v.z) | ((unsigned)f2bf(v.w) << 16);
      xb4[i] = o;
    }
  }
}

// KVt[b][e][d] = sum_ks P[ks*4+b][e][d]   (reduce-only tail)
__global__ __launch_bounds__(256) void reduce_kvt(
    const unsigned short* __restrict__ P, unsigned short* __restrict__ KVt) {
  const long long i = ((long long)blockIdx.x * 256 + threadIdx.x) * 8;
  const int b = (int)(i >> 20);
  const long long ed = i & ((1ll << 20) - 1);
  float s[8] = {0.f, 0.f, 0.f, 0.f, 0.f, 0.f, 0.f, 0.f};
#pragma unroll
  for (int ks = 0; ks < 4; ++ks) {
    u16x8 v = *(const u16x8*)(P + ((long long)(ks * 4 + b) << 20) + ed);
#pragma unroll
    for (int j = 0; j < 8; ++j) s[j] += bf2f(v[j]);
  }
  u16x8 o;
#pragma unroll
  for (int j = 0; j < 8; ++j) o[j] = f2bf(s[j]);
  *(u16x8*)(KVt + i) = o;
}

extern "C" void kernel_launch(void* const* d_in, const int* in_sizes, int n_in,
                              void* d_out, int out_size, void* d_ws,
                              size_t ws_size, hipStream_t stream) {
  const float* x  = (const float*)d_in[0];
  const float* Wq = (const float*)d_in[1];
  const float* bq = (const float*)d_in[2];
  const float* Wk = (const float*)d_in[3];
  const float* bk = (const float*)d_in[4];
  const float* Wv = (const float*)d_in[5];
  const float* bv = (const float*)d_in[6];
  float* out = (float*)d_out;

  const size_t MN = 16384ull * 1024ull;
  char* w = (char*)d_ws;
  unsigned short* xb  = (unsigned short*)w;  w += MN * 2;
  unsigned short* WT  = (unsigned short*)w;  w += 3ull * 1024 * 1024 * 2;
  unsigned short* Qp  = (unsigned short*)w;  w += MN * 2;
  unsigned short* KVb = (unsigned short*)w;  w += 2 * MN * 2;
  unsigned short* KVt = (unsigned short*)w;  w += 4ull * 1024 * 1024 * 2;
  float* Ksum = (float*)w;  w += 4ull * 1024 * 4;
  unsigned short* Pkv = xb;  // split-K partials alias dead xb
  unsigned short* KpT = KVb;
  unsigned short* VT  = KVb + MN;

  // 1) W transposes + x conversion
  prep_fused<<<dim3(32, 32, 4), 256, 0, stream>>>(Wq, Wk, Wv, WT,
                                                  (const float4*)x, (uint2*)xb);
  // 2) Qp + merged KV projection (one 768-block launch; KVproj first)
  proj_fused<<<768, 1024, 0, stream>>>(xb, WT, Qp, KVb, bq, bk, bv);
  // 3) split-K KVt partials + fused ksum (z==16 slice)
  splitk_ksum<<<dim3(4, 4, 17), 1024, 0, stream>>>(VT, KpT, Pkv, Ksum);
  // 4) KVt reduce
  reduce_kvt<<<2048, 256, 0, stream>>>(Pkv, KVt);
  // 5) numerator with fused per-block norm
  gemm_num<<<dim3(4, 16, 4), 512, 0, stream>>>(
      Qp, 4096ll * 1024, KVt, 1024 * 1024, out, 4096ll * 1024, Ksum);
}

// Round 16
// 238.912 us; speedup vs baseline: 1.1045x; 1.1045x over previous
//
#include <hip/hip_runtime.h>
#include <hip/hip_bf16.h>
#include <cstdint>

typedef __bf16 bf16x8 __attribute__((ext_vector_type(8)));
typedef float  f32x4  __attribute__((ext_vector_type(4)));
typedef unsigned short u16x8 __attribute__((ext_vector_type(8)));

__device__ __forceinline__ unsigned short f2bf(float f) {
  __hip_bfloat16 h = __float2bfloat16(f);
  return __builtin_bit_cast(unsigned short, h);
}
__device__ __forceinline__ float bf2f(unsigned short u) {
  return __builtin_bit_cast(float, (unsigned)u << 16);
}

#define GL2LDS16(gp, lp)                                                      \
  __builtin_amdgcn_global_load_lds(                                           \
      (const __attribute__((address_space(1))) unsigned int*)(gp),            \
      (__attribute__((address_space(3))) unsigned int*)(lp), 16, 0, 0)

#define SBAR                                                                  \
  {                                                                           \
    __builtin_amdgcn_s_barrier();                                             \
    __builtin_amdgcn_sched_barrier(0);                                        \
  }
#define WAITV(n)                                                              \
  {                                                                           \
    asm volatile("s_waitcnt vmcnt(" #n ")" ::: "memory");                     \
    __builtin_amdgcn_sched_barrier(0);                                        \
  }
#define WAITL0                                                                \
  {                                                                           \
    asm volatile("s_waitcnt lgkmcnt(0)" ::: "memory");                        \
    __builtin_amdgcn_sched_barrier(0);                                        \
  }

// ===== Merged projection kernel (R14-verified BEST, byte-identical): Qp AND
// KV-proj in one 768-block launch. Blocks h<512: KV-proj (A=[WkT;WvT], B=xb,
// C=KVb[2048][16384], col-stripe XCD decode); h>=512: Qp.
// Core = 256x256 tile, 16 waves, per-wave 64x64, BK=32, 3-slot 96KB ring,
// launch_bounds(1024,4) -> 64 VGPR ((1024,8) forces 32 VGPR + spill, R10).
// Loop: {stage(t+2); 8 ds_read(t); lgkm0; 16 MFMA; vmcnt(2); s_barrier}.
// Swizzle phys = l ^ (((l>>7)&3)<<4) on BOTH pre-swizzled global source and
// ds_read address (involution; 0 bank conflicts measured).
// R15 lesson (reverted): piggybacking ksum as 16 grid-blocks collapsed its
// parallelism (32MB on 16 CUs + 272>256 blocks -> extra chip round, -25us).
__global__ __launch_bounds__(1024, 4) void proj_fused(
    const unsigned short* __restrict__ xb, const unsigned short* __restrict__ WT,
    unsigned short* __restrict__ QpO, unsigned short* __restrict__ KVbO,
    const float* __restrict__ bq, const float* __restrict__ bk,
    const float* __restrict__ bv) {
  __shared__ __attribute__((aligned(16))) char lds[3 * 32768];
  const int t = threadIdx.x;
  const int wave = t >> 6, lane = t & 63;
  const int wm = wave >> 2, wn = wave & 3;
  const int fr = lane & 15, fq = lane >> 4;

  const int h = blockIdx.x;
  const bool kv = (h < 512);
  const unsigned short* A;
  const unsigned short* B;
  unsigned short* Cc;
  long long ldc;
  int m0, n0;
  if (kv) {
    const int f = (h & 7) * 64 + (h >> 3);  // bijective XCD chunk over 512
    const int bx = f >> 3, by = f & 7;      // col-major: A (4MB) L2-resident
    m0 = by * 256;
    n0 = bx * 256;
    A = WT + 1024 * 1024;  // [WkT;WvT] rows 0..2047
    B = xb;
    Cc = KVbO;
    ldc = 16384;
  } else {
    const int hh = h - 512;
    const int f = (hh & 7) * 32 + (hh >> 3);  // chunk over 256
    const int bx = f & 3, by = f >> 2;
    m0 = by * 256;
    n0 = bx * 256;
    A = xb;
    B = WT;
    Cc = QpO;
    ldc = 1024;
  }

  const unsigned short* gA;
  const unsigned short* gB;
  {
    int d = t * 16;
    int l = d ^ (((d >> 7) & 3) << 4);
    int row = l >> 6, kel = (l & 63) >> 1;
    gA = A + (long long)(m0 + row) * 1024 + kel;
    gB = B + (long long)(n0 + row) * 1024 + kel;
  }

  const int slotx = (fr >> 1) & 3;
  const int acore = wm * 4096 + fr * 64 + ((fq ^ slotx) << 4);
  const int bcore = 16384 + wn * 4096 + fr * 64 + ((fq ^ slotx) << 4);

  f32x4 acc[4][4];
#pragma unroll
  for (int i = 0; i < 4; ++i)
#pragma unroll
    for (int j = 0; j < 4; ++j) acc[i][j] = (f32x4){0.f, 0.f, 0.f, 0.f};

  const int NT = 32;  // K=1024, BK=32

  auto stage = [&](int tile) {
    char* sb = lds + (tile % 3) * 32768 + wave * 1024;
    const int k0 = tile << 5;
    GL2LDS16(gA + k0, sb);
    GL2LDS16(gB + k0, sb + 16384);
  };

  stage(0);
  stage(1);
  WAITV(2);
  SBAR;

  bf16x8 av[4], bv4[4];
  for (int tt = 0; tt < NT - 2; ++tt) {
    const char* sb = lds + (tt % 3) * 32768;
    stage(tt + 2);
#pragma unroll
    for (int i = 0; i < 4; ++i) {
      av[i] = *(const bf16x8*)(sb + acore + i * 1024);
      bv4[i] = *(const bf16x8*)(sb + bcore + i * 1024);
    }
    WAITL0;
    __builtin_amdgcn_s_setprio(1);
#pragma unroll
    for (int mi = 0; mi < 4; ++mi)
#pragma unroll
      for (int ni = 0; ni < 4; ++ni)
        acc[mi][ni] = __builtin_amdgcn_mfma_f32_16x16x32_bf16(
            av[mi], bv4[ni], acc[mi][ni], 0, 0, 0);
    __builtin_amdgcn_s_setprio(0);
    WAITV(2);
    SBAR;
  }
  {
    const char* sb = lds + ((NT - 2) % 3) * 32768;
#pragma unroll
    for (int i = 0; i < 4; ++i) {
      av[i] = *(const bf16x8*)(sb + acore + i * 1024);
      bv4[i] = *(const bf16x8*)(sb + bcore + i * 1024);
    }
    WAITL0;
#pragma unroll
    for (int mi = 0; mi < 4; ++mi)
#pragma unroll
      for (int ni = 0; ni < 4; ++ni)
        acc[mi][ni] = __builtin_amdgcn_mfma_f32_16x16x32_bf16(
            av[mi], bv4[ni], acc[mi][ni], 0, 0, 0);
    WAITV(0);
    SBAR;
  }
  {
    const char* sb = lds + ((NT - 1) % 3) * 32768;
#pragma unroll
    for (int i = 0; i < 4; ++i) {
      av[i] = *(const bf16x8*)(sb + acore + i * 1024);
      bv4[i] = *(const bf16x8*)(sb + bcore + i * 1024);
    }
    WAITL0;
#pragma unroll
    for (int mi = 0; mi < 4; ++mi)
#pragma unroll
      for (int ni = 0; ni < 4; ++ni)
        acc[mi][ni] = __builtin_amdgcn_mfma_f32_16x16x32_bf16(
            av[mi], bv4[ni], acc[mi][ni], 0, 0, 0);
  }

  // epilogue. C/D: col = lane&15, row = (lane>>4)*4 + j [m89]
  const bool lower = (m0 < 1024);  // KV role: KpT half vs VT half
#pragma unroll
  for (int mi = 0; mi < 4; ++mi) {
    const int rbase = m0 + wm * 64 + mi * 16 + fq * 4;
    float rb[4];
#pragma unroll
    for (int j = 0; j < 4; ++j)
      if (kv) rb[j] = lower ? bk[rbase + j] : bv[rbase - 1024 + j];
#pragma unroll
    for (int ni = 0; ni < 4; ++ni) {
      const int c = n0 + wn * 64 + ni * 16 + fr;
      const float cb = kv ? 0.f : bq[c];
#pragma unroll
      for (int j = 0; j < 4; ++j) {
        float v = acc[mi][ni][j];
        v += kv ? rb[j] : cb;
        if (!kv || lower) v = (v > 0.f) ? v + 1.f : __expf(v);
        Cc[(long long)(rbase + j) * ldc + c] = f2bf(v);
      }
    }
  }
}

// ===== split-K KVt partials (R13 core, 256 blocks = exactly 1 chip round) ==
__global__ __launch_bounds__(1024, 4) void gemm_splitk(
    const unsigned short* __restrict__ A, const unsigned short* __restrict__ B,
    unsigned short* __restrict__ C) {
  __shared__ __attribute__((aligned(16))) char lds[3 * 32768];
  const int t = threadIdx.x;
  const int wave = t >> 6, lane = t & 63;
  const int wm = wave >> 2, wn = wave & 3;
  const int fr = lane & 15, fq = lane >> 4;

  const int gx = gridDim.x, gy = gridDim.y;
  int flat = blockIdx.y * gx + blockIdx.x;
  const int total = gx * gy;
  if ((total & 7) == 0) flat = (flat & 7) * (total >> 3) + (flat >> 3);
  const int bx = flat % gx, by = flat / gx;
  const int m0 = by * 256, n0 = bx * 256;

  const long long z = blockIdx.z;
  const long long koff = (z & 3) * 4096 + (z >> 2) * 1024;
  const unsigned short* Az = A + koff;
  const unsigned short* Bz = B + koff;

  const unsigned short* gA;
  const unsigned short* gB;
  {
    int d = t * 16;
    int l = d ^ (((d >> 7) & 3) << 4);
    int row = l >> 6, kel = (l & 63) >> 1;
    gA = Az + (long long)(m0 + row) * 16384 + kel;
    gB = Bz + (long long)(n0 + row) * 16384 + kel;
  }

  const int slotx = (fr >> 1) & 3;
  const int acore = wm * 4096 + fr * 64 + ((fq ^ slotx) << 4);
  const int bcore = 16384 + wn * 4096 + fr * 64 + ((fq ^ slotx) << 4);

  f32x4 acc[4][4];
#pragma unroll
  for (int i = 0; i < 4; ++i)
#pragma unroll
    for (int j = 0; j < 4; ++j) acc[i][j] = (f32x4){0.f, 0.f, 0.f, 0.f};

  const int NT = 32;

  auto stage = [&](int tile) {
    char* sb = lds + (tile % 3) * 32768 + wave * 1024;
    const int k0 = tile << 5;
    GL2LDS16(gA + k0, sb);
    GL2LDS16(gB + k0, sb + 16384);
  };

  stage(0);
  stage(1);
  WAITV(2);
  SBAR;

  bf16x8 av[4], bv[4];
  for (int tt = 0; tt < NT - 2; ++tt) {
    const char* sb = lds + (tt % 3) * 32768;
    stage(tt + 2);
#pragma unroll
    for (int i = 0; i < 4; ++i) {
      av[i] = *(const bf16x8*)(sb + acore + i * 1024);
      bv[i] = *(const bf16x8*)(sb + bcore + i * 1024);
    }
    WAITL0;
    __builtin_amdgcn_s_setprio(1);
#pragma unroll
    for (int mi = 0; mi < 4; ++mi)
#pragma unroll
      for (int ni = 0; ni < 4; ++ni)
        acc[mi][ni] = __builtin_amdgcn_mfma_f32_16x16x32_bf16(
            av[mi], bv[ni], acc[mi][ni], 0, 0, 0);
    __builtin_amdgcn_s_setprio(0);
    WAITV(2);
    SBAR;
  }
  {
    const char* sb = lds + ((NT - 2) % 3) * 32768;
#pragma unroll
    for (int i = 0; i < 4; ++i) {
      av[i] = *(const bf16x8*)(sb + acore + i * 1024);
      bv[i] = *(const bf16x8*)(sb + bcore + i * 1024);
    }
    WAITL0;
#pragma unroll
    for (int mi = 0; mi < 4; ++mi)
#pragma unroll
      for (int ni = 0; ni < 4; ++ni)
        acc[mi][ni] = __builtin_amdgcn_mfma_f32_16x16x32_bf16(
            av[mi], bv[ni], acc[mi][ni], 0, 0, 0);
    WAITV(0);
    SBAR;
  }
  {
    const char* sb = lds + ((NT - 1) % 3) * 32768;
#pragma unroll
    for (int i = 0; i < 4; ++i) {
      av[i] = *(const bf16x8*)(sb + acore + i * 1024);
      bv[i] = *(const bf16x8*)(sb + bcore + i * 1024);
    }
    WAITL0;
#pragma unroll
    for (int mi = 0; mi < 4; ++mi)
#pragma unroll
      for (int ni = 0; ni < 4; ++ni)
        acc[mi][ni] = __builtin_amdgcn_mfma_f32_16x16x32_bf16(
            av[mi], bv[ni], acc[mi][ni], 0, 0, 0);
  }

  unsigned short* Cu = C + blockIdx.z * 1048576ll;
#pragma unroll
  for (int mi = 0; mi < 4; ++mi) {
    const int rbase = m0 + wm * 64 + mi * 16 + fq * 4;
#pragma unroll
    for (int ni = 0; ni < 4; ++ni) {
      const int c = n0 + wn * 64 + ni * 16 + fr;
#pragma unroll
      for (int j = 0; j < 4; ++j)
        Cu[(long long)(rbase + j) * 1024 + c] = f2bf(acc[mi][ni][j]);
    }
  }
}

// ===== numerator: R13 8-wave BK=64 4-phase kernel (norm via global nrm) ====
__global__ __launch_bounds__(512, 2) void gemm_num(
    const unsigned short* __restrict__ A, long long aOffZ,
    const unsigned short* __restrict__ B, long long bOffZ,
    float* __restrict__ C, long long cOffZ,
    const float* __restrict__ norm, long long normOffZ) {
  const long long lda = 1024, ldb = 1024, ldc = 1024;
  const int K = 1024;
  __shared__ __attribute__((aligned(16))) char lds[2 * 65536];
  const int t = threadIdx.x;
  const int wave = t >> 6, lane = t & 63;
  const int wm = wave >> 2, wn = wave & 3;
  const int fr = lane & 15, fq = lane >> 4;

  const int gx = gridDim.x, gy = gridDim.y;
  int flat = blockIdx.y * gx + blockIdx.x;
  const int total = gx * gy;
  if ((total & 7) == 0) flat = (flat & 7) * (total >> 3) + (flat >> 3);
  const int bx = flat % gx, by = flat / gx;
  const int m0 = by * 256, n0 = bx * 256;

  const long long z = blockIdx.z;
  const unsigned short* Az = A + z * aOffZ;
  const unsigned short* Bz = B + z * bOffZ;

  const unsigned short* gA[2];
  const unsigned short* gB[2];
#pragma unroll
  for (int c = 0; c < 2; ++c) {
    int d = c * 8192 + t * 16;
    int l = d ^ (((d >> 7) & 3) << 4);
    int row = l >> 6, kel = (l & 63) >> 1;
    gA[c] = Az + (long long)(m0 + row) * lda + kel;
    gB[c] = Bz + (long long)(n0 + row) * ldb + kel;
  }

  const int slotx = (fr >> 1) & 3;
  const int acore = wm * 8192 + fr * 64 + ((fq ^ slotx) << 4);
  const int bcore = wn * 4096 + fr * 64 + ((fq ^ slotx) << 4);

  f32x4 acc[8][4];
#pragma unroll
  for (int i = 0; i < 8; ++i)
#pragma unroll
    for (int j = 0; j < 4; ++j) acc[i][j] = (f32x4){0.f, 0.f, 0.f, 0.f};

  const int NT = K >> 6;

  auto stage_sub = [&](int tile, int which) {
    char* dst = lds + (tile & 1) * 65536 + which * 16384 + wave * 1024;
    const int kofs = (tile << 6) + ((which >> 1) << 5);
    if (which & 1) {
      GL2LDS16(gB[0] + kofs, dst);
      GL2LDS16(gB[1] + kofs, dst + 8192);
    } else {
      GL2LDS16(gA[0] + kofs, dst);
      GL2LDS16(gA[1] + kofs, dst + 8192);
    }
  };

  stage_sub(0, 0);
  stage_sub(0, 1);
  stage_sub(0, 2);
  stage_sub(0, 3);
  WAITV(4);
  SBAR;

  bf16x8 av[4], bv0[4], bv1[4];
  for (int tt = 0; tt < NT - 1; ++tt) {
    const char* bufp = lds + (tt & 1) * 65536;
#pragma unroll
    for (int i = 0; i < 4; ++i) {
      av[i] = *(const bf16x8*)(bufp + acore + i * 1024);
      bv0[i] = *(const bf16x8*)(bufp + 16384 + bcore + i * 1024);
    }
    stage_sub(tt + 1, 0);
    SBAR;
    WAITL0;
    __builtin_amdgcn_s_setprio(1);
#pragma unroll
    for (int mi = 0; mi < 4; ++mi)
#pragma unroll
      for (int ni = 0; ni < 4; ++ni)
        acc[mi][ni] = __builtin_amdgcn_mfma_f32_16x16x32_bf16(
            av[mi], bv0[ni], acc[mi][ni], 0, 0, 0);
    __builtin_amdgcn_s_setprio(0);
    SBAR;
#pragma unroll
    for (int i = 0; i < 4; ++i)
      av[i] = *(const bf16x8*)(bufp + acore + (4 + i) * 1024);
    stage_sub(tt + 1, 1);
    SBAR;
    WAITL0;
    __builtin_amdgcn_s_setprio(1);
#pragma unroll
    for (int mi = 0; mi < 4; ++mi)
#pragma unroll
      for (int ni = 0; ni < 4; ++ni)
        acc[4 + mi][ni] = __builtin_amdgcn_mfma_f32_16x16x32_bf16(
            av[mi], bv0[ni], acc[4 + mi][ni], 0, 0, 0);
    __builtin_amdgcn_s_setprio(0);
    WAITV(4);
    SBAR;
#pragma unroll
    for (int i = 0; i < 4; ++i) {
      av[i] = *(const bf16x8*)(bufp + 32768 + acore + i * 1024);
      bv1[i] = *(const bf16x8*)(bufp + 49152 + bcore + i * 1024);
    }
    stage_sub(tt + 1, 2);
    SBAR;
    WAITL0;
    __builtin_amdgcn_s_setprio(1);
#pragma unroll
    for (int mi = 0; mi < 4; ++mi)
#pragma unroll
      for (int ni = 0; ni < 4; ++ni)
        acc[mi][ni] = __builtin_amdgcn_mfma_f32_16x16x32_bf16(
            av[mi], bv1[ni], acc[mi][ni], 0, 0, 0);
    __builtin_amdgcn_s_setprio(0);
    SBAR;
#pragma unroll
    for (int i = 0; i < 4; ++i)
      av[i] = *(const bf16x8*)(bufp + 32768 + acore + (4 + i) * 1024);
    stage_sub(tt + 1, 3);
    SBAR;
    WAITL0;
    __builtin_amdgcn_s_setprio(1);
#pragma unroll
    for (int mi = 0; mi < 4; ++mi)
#pragma unroll
      for (int ni = 0; ni < 4; ++ni)
        acc[4 + mi][ni] = __builtin_amdgcn_mfma_f32_16x16x32_bf16(
            av[mi], bv1[ni], acc[4 + mi][ni], 0, 0, 0);
    __builtin_amdgcn_s_setprio(0);
    WAITV(4);
    SBAR;
  }
  {
    const char* bufp = lds + ((NT - 1) & 1) * 65536;
#pragma unroll
    for (int i = 0; i < 4; ++i) {
      av[i] = *(const bf16x8*)(bufp + acore + i * 1024);
      bv0[i] = *(const bf16x8*)(bufp + 16384 + bcore + i * 1024);
    }
    SBAR;
    WAITL0;
#pragma unroll
    for (int mi = 0; mi < 4; ++mi)
#pragma unroll
      for (int ni = 0; ni < 4; ++ni)
        acc[mi][ni] = __builtin_amdgcn_mfma_f32_16x16x32_bf16(
            av[mi], bv0[ni], acc[mi][ni], 0, 0, 0);
    SBAR;
#pragma unroll
    for (int i = 0; i < 4; ++i)
      av[i] = *(const bf16x8*)(bufp + acore + (4 + i) * 1024);
    SBAR;
    WAITL0;
#pragma unroll
    for (int mi = 0; mi < 4; ++mi)
#pragma unroll
      for (int ni = 0; ni < 4; ++ni)
        acc[4 + mi][ni] = __builtin_amdgcn_mfma_f32_16x16x32_bf16(
            av[mi], bv0[ni], acc[4 + mi][ni], 0, 0, 0);
    WAITV(0);
    SBAR;
#pragma unroll
    for (int i = 0; i < 4; ++i) {
      av[i] = *(const bf16x8*)(bufp + 32768 + acore + i * 1024);
      bv1[i] = *(const bf16x8*)(bufp + 49152 + bcore + i * 1024);
    }
    WAITL0;
#pragma unroll
    for (int mi = 0; mi < 4; ++mi)
#pragma unroll
      for (int ni = 0; ni < 4; ++ni)
        acc[mi][ni] = __builtin_amdgcn_mfma_f32_16x16x32_bf16(
            av[mi], bv1[ni], acc[mi][ni], 0, 0, 0);
#pragma unroll
    for (int i = 0; i < 4; ++i)
      av[i] = *(const bf16x8*)(bufp + 32768 + acore + (4 + i) * 1024);
    WAITL0;
#pragma unroll
    for (int mi = 0; mi < 4; ++mi)
#pragma unroll
      for (int ni = 0; ni < 4; ++ni)
        acc[4 + mi][ni] = __builtin_amdgcn_mfma_f32_16x16x32_bf16(
            av[mi], bv1[ni], acc[4 + mi][ni], 0, 0, 0);
  }

  const float* nrmz = norm + z * normOffZ;
  float* Cf = C + z * cOffZ;
#pragma unroll
  for (int mi = 0; mi < 8; ++mi) {
    const int rbase = m0 + wm * 128 + mi * 16 + fq * 4;
    float nv[4];
#pragma unroll
    for (int j = 0; j < 4; ++j) nv[j] = nrmz[rbase + j];
#pragma unroll
    for (int ni = 0; ni < 4; ++ni) {
      const int c = n0 + wn * 64 + ni * 16 + fr;
#pragma unroll
      for (int j = 0; j < 4; ++j)
        Cf[(long long)(rbase + j) * ldc + c] = acc[mi][ni][j] / nv[j];
    }
  }
}

// ===== prep: 3x W-transpose + x->bf16 convert in one launch (z in 0..3) ===
__global__ __launch_bounds__(256) void prep_fused(
    const float* __restrict__ Wq, const float* __restrict__ Wk,
    const float* __restrict__ Wv, unsigned short* __restrict__ WT,
    const float4* __restrict__ x4, uint2* __restrict__ xb4) {
  __shared__ float tile[32][33];
  if (blockIdx.z < 3) {
    const float* W = blockIdx.z == 0 ? Wq : (blockIdx.z == 1 ? Wk : Wv);
    unsigned short* out = WT + (size_t)blockIdx.z * 1024 * 1024;
    const int tx = threadIdx.x & 31, ty = threadIdx.x >> 5;
    const int i0 = blockIdx.y * 32, o0 = blockIdx.x * 32;
#pragma unroll
    for (int s = 0; s < 32; s += 8)
      tile[ty + s][tx] = W[(long long)(i0 + ty + s) * 1024 + o0 + tx];
    __syncthreads();
#pragma unroll
    for (int s = 0; s < 32; s += 8)
      out[(long long)(o0 + ty + s) * 1024 + i0 + tx] = f2bf(tile[tx][ty + s]);
  } else {
    const int flat = blockIdx.y * 32 + blockIdx.x;  // 0..1023
    const int n4 = 4194304;                          // 16384*1024/4
    for (int i = flat * 256 + threadIdx.x; i < n4; i += 1024 * 256) {
      float4 v = x4[i];
      uint2 o;
      o.x = (unsigned)f2bf(v.x) | ((unsigned)f2bf(v.y) << 16);
      o.y = (unsigned)f2bf(v.z) | ((unsigned)f2bf(v.w) << 16);
      xb4[i] = o;
    }
  }
}

// K_sum[b][d] = sum_n KpT[d][b*4096 + n]  (full-chip 1024-block launch)
__global__ __launch_bounds__(256) void ksum_kernel(
    const unsigned short* __restrict__ KpT, float* __restrict__ Ksum) {
  const int gw = (blockIdx.x * 256 + threadIdx.x) >> 6;
  const int lane = threadIdx.x & 63;
  const int d = gw >> 2, b = gw & 3;
  const unsigned short* p = KpT + (long long)d * 16384 + b * 4096 + lane * 8;
  float s = 0.f;
#pragma unroll
  for (int it = 0; it < 8; ++it) {
    u16x8 v = *(const u16x8*)(p + it * 512);
#pragma unroll
    for (int j = 0; j < 8; ++j) s += bf2f(v[j]);
  }
#pragma unroll
  for (int o = 32; o > 0; o >>= 1) s += __shfl_down(s, o, 64);
  if (lane == 0) Ksum[b * 1024 + d] = s;
}

// ===== tail: KVt reduce (blocks <2048) + norm (blocks >=2048), one launch ==
__global__ __launch_bounds__(256) void tail_fused(
    const unsigned short* __restrict__ P, unsigned short* __restrict__ KVt,
    const unsigned short* __restrict__ Qp, const float* __restrict__ Ksum,
    float* __restrict__ nrm) {
  if (blockIdx.x < 2048) {
    const long long i = ((long long)blockIdx.x * 256 + threadIdx.x) * 8;
    const int b = (int)(i >> 20);
    const long long ed = i & ((1ll << 20) - 1);
    float s[8] = {0.f, 0.f, 0.f, 0.f, 0.f, 0.f, 0.f, 0.f};
#pragma unroll
    for (int ks = 0; ks < 4; ++ks) {
      u16x8 v = *(const u16x8*)(P + ((long long)(ks * 4 + b) << 20) + ed);
#pragma unroll
      for (int j = 0; j < 8; ++j) s[j] += bf2f(v[j]);
    }
    u16x8 o;
#pragma unroll
    for (int j = 0; j < 8; ++j) o[j] = f2bf(s[j]);
    *(u16x8*)(KVt + i) = o;
  } else {
    const int gw = ((blockIdx.x - 2048) * 256 + threadIdx.x) >> 6;
    const int lane = threadIdx.x & 63;
    const int b = gw >> 12;
    const unsigned short* q = Qp + (long long)gw * 1024 + lane * 8;
    const float* ks = Ksum + b * 1024 + lane * 8;
    float s = 0.f;
#pragma unroll
    for (int it = 0; it < 2; ++it) {
      u16x8 v = *(const u16x8*)(q + it * 512);
      float4 k0 = *(const float4*)(ks + it * 512);
      float4 k1 = *(const float4*)(ks + it * 512 + 4);
      s += bf2f(v[0]) * k0.x + bf2f(v[1]) * k0.y + bf2f(v[2]) * k0.z +
           bf2f(v[3]) * k0.w + bf2f(v[4]) * k1.x + bf2f(v[5]) * k1.y +
           bf2f(v[6]) * k1.z + bf2f(v[7]) * k1.w;
    }
#pragma unroll
    for (int o = 32; o > 0; o >>= 1) s += __shfl_down(s, o, 64);
    if (lane == 0) nrm[gw] = s + 1e-6f;
  }
}

extern "C" void kernel_launch(void* const* d_in, const int* in_sizes, int n_in,
                              void* d_out, int out_size, void* d_ws,
                              size_t ws_size, hipStream_t stream) {
  const float* x  = (const float*)d_in[0];
  const float* Wq = (const float*)d_in[1];
  const float* bq = (const float*)d_in[2];
  const float* Wk = (const float*)d_in[3];
  const float* bk = (const float*)d_in[4];
  const float* Wv = (const float*)d_in[5];
  const float* bv = (const float*)d_in[6];
  float* out = (float*)d_out;

  const size_t MN = 16384ull * 1024ull;
  char* w = (char*)d_ws;
  unsigned short* xb  = (unsigned short*)w;  w += MN * 2;
  unsigned short* WT  = (unsigned short*)w;  w += 3ull * 1024 * 1024 * 2;
  unsigned short* Qp  = (unsigned short*)w;  w += MN * 2;
  unsigned short* KVb = (unsigned short*)w;  w += 2 * MN * 2;
  unsigned short* KVt = (unsigned short*)w;  w += 4ull * 1024 * 1024 * 2;
  float* Ksum = (float*)w;  w += 4ull * 1024 * 4;
  float* nrm  = (float*)w;  w += 16384ull * 4;
  unsigned short* Pkv = xb;  // split-K partials alias dead xb
  unsigned short* KpT = KVb;
  unsigned short* VT  = KVb + MN;

  // 1) W transposes + x conversion (one launch)
  prep_fused<<<dim3(32, 32, 4), 256, 0, stream>>>(Wq, Wk, Wv, WT,
                                                  (const float4*)x, (uint2*)xb);
  // 2) Qp + merged KV projection (one 768-block launch; KVproj first)
  proj_fused<<<768, 1024, 0, stream>>>(xb, WT, Qp, KVb, bq, bk, bv);
  // 3) K_sum (full-chip)
  ksum_kernel<<<1024, 256, 0, stream>>>(KpT, Ksum);
  // 4) split-K KVt partials: z = ks*4+b
  gemm_splitk<<<dim3(4, 4, 16), 1024, 0, stream>>>(VT, KpT, Pkv);
  // 5) KVt reduce + norm (one launch)
  tail_fused<<<6144, 256, 0, stream>>>(Pkv, KVt, Qp, Ksum, nrm);
  // 6) numerator
  gemm_num<<<dim3(4, 16, 4), 512, 0, stream>>>(
      Qp, 4096ll * 1024, KVt, 1024 * 1024, out, 4096ll * 1024, nrm, 4096);
}

// Round 17
// 237.631 us; speedup vs baseline: 1.1105x; 1.0054x over previous
//
#include <hip/hip_runtime.h>
#include <hip/hip_bf16.h>
#include <cstdint>

typedef __bf16 bf16x8 __attribute__((ext_vector_type(8)));
typedef float  f32x4  __attribute__((ext_vector_type(4)));
typedef unsigned short u16x8 __attribute__((ext_vector_type(8)));

__device__ __forceinline__ unsigned short f2bf(float f) {
  __hip_bfloat16 h = __float2bfloat16(f);
  return __builtin_bit_cast(unsigned short, h);
}
__device__ __forceinline__ float bf2f(unsigned short u) {
  return __builtin_bit_cast(float, (unsigned)u << 16);
}

#define GL2LDS16(gp, lp)                                                      \
  __builtin_amdgcn_global_load_lds(                                           \
      (const __attribute__((address_space(1))) unsigned int*)(gp),            \
      (__attribute__((address_space(3))) unsigned int*)(lp), 16, 0, 0)

#define SBAR                                                                  \
  {                                                                           \
    __builtin_amdgcn_s_barrier();                                             \
    __builtin_amdgcn_sched_barrier(0);                                        \
  }
#define WAITV(n)                                                              \
  {                                                                           \
    asm volatile("s_waitcnt vmcnt(" #n ")" ::: "memory");                     \
    __builtin_amdgcn_sched_barrier(0);                                        \
  }
#define WAITL0                                                                \
  {                                                                           \
    asm volatile("s_waitcnt lgkmcnt(0)" ::: "memory");                        \
    __builtin_amdgcn_sched_barrier(0);                                        \
  }

// ===== Merged projection kernel (R14-verified BEST): Qp AND KV-proj in one
// 768-block launch (= exactly 3 chip rounds, no tail bubble). Blocks h<512:
// KV-proj (A=[WkT;WvT], B=xb, C=KVb[2048][16384], col-stripe XCD decode so
// the 4MB A stays L2-resident); h>=512: Qp.
// Core: 256x256 tile, 16 waves, per-wave 64x64 (4Mx4N optimal: LDS-read
// amplification 4x is the minimum), BK=32, 3-slot 96KB ring,
// launch_bounds(1024,4) -> 64 VGPR. ((1024,8) forces 32 VGPR + catastrophic
// scratch spill - R10. Per-SIMD RF is 512 regs, not the per-CU 2048.)
// Loop: {stage(t+2); 8 ds_read(t); lgkm0; 16 MFMA; vmcnt(2); s_barrier} -
// FIFO-proven lookahead-2; never vmcnt(0) in the loop.
// Swizzle phys = l ^ (((l>>7)&3)<<4) on BOTH pre-swizzled global source and
// ds_read address (involution; 0 bank conflicts measured).
// Session ceiling note: this structure class sustains ~34% MfmaUtil
// (LDS 512cy vs MFMA 310cy per K-tile + barrier lockstep); 5 attempts at
// the 8-phase class (R5/R6/R8/R10/R11) did not beat it.
__global__ __launch_bounds__(1024, 4) void proj_fused(
    const unsigned short* __restrict__ xb, const unsigned short* __restrict__ WT,
    unsigned short* __restrict__ QpO, unsigned short* __restrict__ KVbO,
    const float* __restrict__ bq, const float* __restrict__ bk,
    const float* __restrict__ bv) {
  __shared__ __attribute__((aligned(16))) char lds[3 * 32768];
  const int t = threadIdx.x;
  const int wave = t >> 6, lane = t & 63;
  const int wm = wave >> 2, wn = wave & 3;
  const int fr = lane & 15, fq = lane >> 4;

  const int h = blockIdx.x;
  const bool kv = (h < 512);
  const unsigned short* A;
  const unsigned short* B;
  unsigned short* Cc;
  long long ldc;
  int m0, n0;
  if (kv) {
    const int f = (h & 7) * 64 + (h >> 3);  // bijective XCD chunk over 512
    const int bx = f >> 3, by = f & 7;      // col-major: A (4MB) L2-resident
    m0 = by * 256;
    n0 = bx * 256;
    A = WT + 1024 * 1024;  // [WkT;WvT] rows 0..2047
    B = xb;
    Cc = KVbO;
    ldc = 16384;
  } else {
    const int hh = h - 512;
    const int f = (hh & 7) * 32 + (hh >> 3);  // chunk over 256
    const int bx = f & 3, by = f >> 2;
    m0 = by * 256;
    n0 = bx * 256;
    A = xb;
    B = WT;
    Cc = QpO;
    ldc = 1024;
  }

  const unsigned short* gA;
  const unsigned short* gB;
  {
    int d = t * 16;
    int l = d ^ (((d >> 7) & 3) << 4);
    int row = l >> 6, kel = (l & 63) >> 1;
    gA = A + (long long)(m0 + row) * 1024 + kel;
    gB = B + (long long)(n0 + row) * 1024 + kel;
  }

  const int slotx = (fr >> 1) & 3;
  const int acore = wm * 4096 + fr * 64 + ((fq ^ slotx) << 4);
  const int bcore = 16384 + wn * 4096 + fr * 64 + ((fq ^ slotx) << 4);

  f32x4 acc[4][4];
#pragma unroll
  for (int i = 0; i < 4; ++i)
#pragma unroll
    for (int j = 0; j < 4; ++j) acc[i][j] = (f32x4){0.f, 0.f, 0.f, 0.f};

  const int NT = 32;  // K=1024, BK=32

  auto stage = [&](int tile) {
    char* sb = lds + (tile % 3) * 32768 + wave * 1024;
    const int k0 = tile << 5;
    GL2LDS16(gA + k0, sb);
    GL2LDS16(gB + k0, sb + 16384);
  };

  stage(0);
  stage(1);
  WAITV(2);
  SBAR;

  bf16x8 av[4], bv4[4];
  for (int tt = 0; tt < NT - 2; ++tt) {
    const char* sb = lds + (tt % 3) * 32768;
    stage(tt + 2);
#pragma unroll
    for (int i = 0; i < 4; ++i) {
      av[i] = *(const bf16x8*)(sb + acore + i * 1024);
      bv4[i] = *(const bf16x8*)(sb + bcore + i * 1024);
    }
    WAITL0;
    __builtin_amdgcn_s_setprio(1);
#pragma unroll
    for (int mi = 0; mi < 4; ++mi)
#pragma unroll
      for (int ni = 0; ni < 4; ++ni)
        acc[mi][ni] = __builtin_amdgcn_mfma_f32_16x16x32_bf16(
            av[mi], bv4[ni], acc[mi][ni], 0, 0, 0);
    __builtin_amdgcn_s_setprio(0);
    WAITV(2);
    SBAR;
  }
  {
    const char* sb = lds + ((NT - 2) % 3) * 32768;
#pragma unroll
    for (int i = 0; i < 4; ++i) {
      av[i] = *(const bf16x8*)(sb + acore + i * 1024);
      bv4[i] = *(const bf16x8*)(sb + bcore + i * 1024);
    }
    WAITL0;
#pragma unroll
    for (int mi = 0; mi < 4; ++mi)
#pragma unroll
      for (int ni = 0; ni < 4; ++ni)
        acc[mi][ni] = __builtin_amdgcn_mfma_f32_16x16x32_bf16(
            av[mi], bv4[ni], acc[mi][ni], 0, 0, 0);
    WAITV(0);
    SBAR;
  }
  {
    const char* sb = lds + ((NT - 1) % 3) * 32768;
#pragma unroll
    for (int i = 0; i < 4; ++i) {
      av[i] = *(const bf16x8*)(sb + acore + i * 1024);
      bv4[i] = *(const bf16x8*)(sb + bcore + i * 1024);
    }
    WAITL0;
#pragma unroll
    for (int mi = 0; mi < 4; ++mi)
#pragma unroll
      for (int ni = 0; ni < 4; ++ni)
        acc[mi][ni] = __builtin_amdgcn_mfma_f32_16x16x32_bf16(
            av[mi], bv4[ni], acc[mi][ni], 0, 0, 0);
  }

  // epilogue. C/D: col = lane&15, row = (lane>>4)*4 + j [m89]
  const bool lower = (m0 < 1024);  // KV role: KpT half vs VT half
#pragma unroll
  for (int mi = 0; mi < 4; ++mi) {
    const int rbase = m0 + wm * 64 + mi * 16 + fq * 4;
    float rb[4];
#pragma unroll
    for (int j = 0; j < 4; ++j)
      if (kv) rb[j] = lower ? bk[rbase + j] : bv[rbase - 1024 + j];
#pragma unroll
    for (int ni = 0; ni < 4; ++ni) {
      const int c = n0 + wn * 64 + ni * 16 + fr;
      const float cb = kv ? 0.f : bq[c];
#pragma unroll
      for (int j = 0; j < 4; ++j) {
        float v = acc[mi][ni][j];
        v += kv ? rb[j] : cb;
        if (!kv || lower) v = (v > 0.f) ? v + 1.f : __expf(v);
        Cc[(long long)(rbase + j) * ldc + c] = f2bf(v);
      }
    }
  }
}

// ===== split-K KVt partials (R13 core, 256 blocks = exactly 1 chip round) ==
__global__ __launch_bounds__(1024, 4) void gemm_splitk(
    const unsigned short* __restrict__ A, const unsigned short* __restrict__ B,
    unsigned short* __restrict__ C) {
  __shared__ __attribute__((aligned(16))) char lds[3 * 32768];
  const int t = threadIdx.x;
  const int wave = t >> 6, lane = t & 63;
  const int wm = wave >> 2, wn = wave & 3;
  const int fr = lane & 15, fq = lane >> 4;

  const int gx = gridDim.x, gy = gridDim.y;
  int flat = blockIdx.y * gx + blockIdx.x;
  const int total = gx * gy;
  if ((total & 7) == 0) flat = (flat & 7) * (total >> 3) + (flat >> 3);
  const int bx = flat % gx, by = flat / gx;
  const int m0 = by * 256, n0 = bx * 256;

  const long long z = blockIdx.z;
  const long long koff = (z & 3) * 4096 + (z >> 2) * 1024;
  const unsigned short* Az = A + koff;
  const unsigned short* Bz = B + koff;

  const unsigned short* gA;
  const unsigned short* gB;
  {
    int d = t * 16;
    int l = d ^ (((d >> 7) & 3) << 4);
    int row = l >> 6, kel = (l & 63) >> 1;
    gA = Az + (long long)(m0 + row) * 16384 + kel;
    gB = Bz + (long long)(n0 + row) * 16384 + kel;
  }

  const int slotx = (fr >> 1) & 3;
  const int acore = wm * 4096 + fr * 64 + ((fq ^ slotx) << 4);
  const int bcore = 16384 + wn * 4096 + fr * 64 + ((fq ^ slotx) << 4);

  f32x4 acc[4][4];
#pragma unroll
  for (int i = 0; i < 4; ++i)
#pragma unroll
    for (int j = 0; j < 4; ++j) acc[i][j] = (f32x4){0.f, 0.f, 0.f, 0.f};

  const int NT = 32;

  auto stage = [&](int tile) {
    char* sb = lds + (tile % 3) * 32768 + wave * 1024;
    const int k0 = tile << 5;
    GL2LDS16(gA + k0, sb);
    GL2LDS16(gB + k0, sb + 16384);
  };

  stage(0);
  stage(1);
  WAITV(2);
  SBAR;

  bf16x8 av[4], bv[4];
  for (int tt = 0; tt < NT - 2; ++tt) {
    const char* sb = lds + (tt % 3) * 32768;
    stage(tt + 2);
#pragma unroll
    for (int i = 0; i < 4; ++i) {
      av[i] = *(const bf16x8*)(sb + acore + i * 1024);
      bv[i] = *(const bf16x8*)(sb + bcore + i * 1024);
    }
    WAITL0;
    __builtin_amdgcn_s_setprio(1);
#pragma unroll
    for (int mi = 0; mi < 4; ++mi)
#pragma unroll
      for (int ni = 0; ni < 4; ++ni)
        acc[mi][ni] = __builtin_amdgcn_mfma_f32_16x16x32_bf16(
            av[mi], bv[ni], acc[mi][ni], 0, 0, 0);
    __builtin_amdgcn_s_setprio(0);
    WAITV(2);
    SBAR;
  }
  {
    const char* sb = lds + ((NT - 2) % 3) * 32768;
#pragma unroll
    for (int i = 0; i < 4; ++i) {
      av[i] = *(const bf16x8*)(sb + acore + i * 1024);
      bv[i] = *(const bf16x8*)(sb + bcore + i * 1024);
    }
    WAITL0;
#pragma unroll
    for (int mi = 0; mi < 4; ++mi)
#pragma unroll
      for (int ni = 0; ni < 4; ++ni)
        acc[mi][ni] = __builtin_amdgcn_mfma_f32_16x16x32_bf16(
            av[mi], bv[ni], acc[mi][ni], 0, 0, 0);
    WAITV(0);
    SBAR;
  }
  {
    const char* sb = lds + ((NT - 1) % 3) * 32768;
#pragma unroll
    for (int i = 0; i < 4; ++i) {
      av[i] = *(const bf16x8*)(sb + acore + i * 1024);
      bv[i] = *(const bf16x8*)(sb + bcore + i * 1024);
    }
    WAITL0;
#pragma unroll
    for (int mi = 0; mi < 4; ++mi)
#pragma unroll
      for (int ni = 0; ni < 4; ++ni)
        acc[mi][ni] = __builtin_amdgcn_mfma_f32_16x16x32_bf16(
            av[mi], bv[ni], acc[mi][ni], 0, 0, 0);
  }

  unsigned short* Cu = C + blockIdx.z * 1048576ll;
#pragma unroll
  for (int mi = 0; mi < 4; ++mi) {
    const int rbase = m0 + wm * 64 + mi * 16 + fq * 4;
#pragma unroll
    for (int ni = 0; ni < 4; ++ni) {
      const int c = n0 + wn * 64 + ni * 16 + fr;
#pragma unroll
      for (int j = 0; j < 4; ++j)
        Cu[(long long)(rbase + j) * 1024 + c] = f2bf(acc[mi][ni][j]);
    }
  }
}

// ===== numerator: R13 8-wave BK=64 4-phase kernel (norm via global nrm) ====
__global__ __launch_bounds__(512, 2) void gemm_num(
    const unsigned short* __restrict__ A, long long aOffZ,
    const unsigned short* __restrict__ B, long long bOffZ,
    float* __restrict__ C, long long cOffZ,
    const float* __restrict__ norm, long long normOffZ) {
  const long long lda = 1024, ldb = 1024, ldc = 1024;
  const int K = 1024;
  __shared__ __attribute__((aligned(16))) char lds[2 * 65536];
  const int t = threadIdx.x;
  const int wave = t >> 6, lane = t & 63;
  const int wm = wave >> 2, wn = wave & 3;
  const int fr = lane & 15, fq = lane >> 4;

  const int gx = gridDim.x, gy = gridDim.y;
  int flat = blockIdx.y * gx + blockIdx.x;
  const int total = gx * gy;
  if ((total & 7) == 0) flat = (flat & 7) * (total >> 3) + (flat >> 3);
  const int bx = flat % gx, by = flat / gx;
  const int m0 = by * 256, n0 = bx * 256;

  const long long z = blockIdx.z;
  const unsigned short* Az = A + z * aOffZ;
  const unsigned short* Bz = B + z * bOffZ;

  const unsigned short* gA[2];
  const unsigned short* gB[2];
#pragma unroll
  for (int c = 0; c < 2; ++c) {
    int d = c * 8192 + t * 16;
    int l = d ^ (((d >> 7) & 3) << 4);
    int row = l >> 6, kel = (l & 63) >> 1;
    gA[c] = Az + (long long)(m0 + row) * lda + kel;
    gB[c] = Bz + (long long)(n0 + row) * ldb + kel;
  }

  const int slotx = (fr >> 1) & 3;
  const int acore = wm * 8192 + fr * 64 + ((fq ^ slotx) << 4);
  const int bcore = wn * 4096 + fr * 64 + ((fq ^ slotx) << 4);

  f32x4 acc[8][4];
#pragma unroll
  for (int i = 0; i < 8; ++i)
#pragma unroll
    for (int j = 0; j < 4; ++j) acc[i][j] = (f32x4){0.f, 0.f, 0.f, 0.f};

  const int NT = K >> 6;

  auto stage_sub = [&](int tile, int which) {
    char* dst = lds + (tile & 1) * 65536 + which * 16384 + wave * 1024;
    const int kofs = (tile << 6) + ((which >> 1) << 5);
    if (which & 1) {
      GL2LDS16(gB[0] + kofs, dst);
      GL2LDS16(gB[1] + kofs, dst + 8192);
    } else {
      GL2LDS16(gA[0] + kofs, dst);
      GL2LDS16(gA[1] + kofs, dst + 8192);
    }
  };

  stage_sub(0, 0);
  stage_sub(0, 1);
  stage_sub(0, 2);
  stage_sub(0, 3);
  WAITV(4);
  SBAR;

  bf16x8 av[4], bv0[4], bv1[4];
  for (int tt = 0; tt < NT - 1; ++tt) {
    const char* bufp = lds + (tt & 1) * 65536;
#pragma unroll
    for (int i = 0; i < 4; ++i) {
      av[i] = *(const bf16x8*)(bufp + acore + i * 1024);
      bv0[i] = *(const bf16x8*)(bufp + 16384 + bcore + i * 1024);
    }
    stage_sub(tt + 1, 0);
    SBAR;
    WAITL0;
    __builtin_amdgcn_s_setprio(1);
#pragma unroll
    for (int mi = 0; mi < 4; ++mi)
#pragma unroll
      for (int ni = 0; ni < 4; ++ni)
        acc[mi][ni] = __builtin_amdgcn_mfma_f32_16x16x32_bf16(
            av[mi], bv0[ni], acc[mi][ni], 0, 0, 0);
    __builtin_amdgcn_s_setprio(0);
    SBAR;
#pragma unroll
    for (int i = 0; i < 4; ++i)
      av[i] = *(const bf16x8*)(bufp + acore + (4 + i) * 1024);
    stage_sub(tt + 1, 1);
    SBAR;
    WAITL0;
    __builtin_amdgcn_s_setprio(1);
#pragma unroll
    for (int mi = 0; mi < 4; ++mi)
#pragma unroll
      for (int ni = 0; ni < 4; ++ni)
        acc[4 + mi][ni] = __builtin_amdgcn_mfma_f32_16x16x32_bf16(
            av[mi], bv0[ni], acc[4 + mi][ni], 0, 0, 0);
    __builtin_amdgcn_s_setprio(0);
    WAITV(4);
    SBAR;
#pragma unroll
    for (int i = 0; i < 4; ++i) {
      av[i] = *(const bf16x8*)(bufp + 32768 + acore + i * 1024);
      bv1[i] = *(const bf16x8*)(bufp + 49152 + bcore + i * 1024);
    }
    stage_sub(tt + 1, 2);
    SBAR;
    WAITL0;
    __builtin_amdgcn_s_setprio(1);
#pragma unroll
    for (int mi = 0; mi < 4; ++mi)
#pragma unroll
      for (int ni = 0; ni < 4; ++ni)
        acc[mi][ni] = __builtin_amdgcn_mfma_f32_16x16x32_bf16(
            av[mi], bv1[ni], acc[mi][ni], 0, 0, 0);
    __builtin_amdgcn_s_setprio(0);
    SBAR;
#pragma unroll
    for (int i = 0; i < 4; ++i)
      av[i] = *(const bf16x8*)(bufp + 32768 + acore + (4 + i) * 1024);
    stage_sub(tt + 1, 3);
    SBAR;
    WAITL0;
    __builtin_amdgcn_s_setprio(1);
#pragma unroll
    for (int mi = 0; mi < 4; ++mi)
#pragma unroll
      for (int ni = 0; ni < 4; ++ni)
        acc[4 + mi][ni] = __builtin_amdgcn_mfma_f32_16x16x32_bf16(
            av[mi], bv1[ni], acc[4 + mi][ni], 0, 0, 0);
    __builtin_amdgcn_s_setprio(0);
    WAITV(4);
    SBAR;
  }
  {
    const char* bufp = lds + ((NT - 1) & 1) * 65536;
#pragma unroll
    for (int i = 0; i < 4; ++i) {
      av[i] = *(const bf16x8*)(bufp + acore + i * 1024);
      bv0[i] = *(const bf16x8*)(bufp + 16384 + bcore + i * 1024);
    }
    SBAR;
    WAITL0;
#pragma unroll
    for (int mi = 0; mi < 4; ++mi)
#pragma unroll
      for (int ni = 0; ni < 4; ++ni)
        acc[mi][ni] = __builtin_amdgcn_mfma_f32_16x16x32_bf16(
            av[mi], bv0[ni], acc[mi][ni], 0, 0, 0);
    SBAR;
#pragma unroll
    for (int i = 0; i < 4; ++i)
      av[i] = *(const bf16x8*)(bufp + acore + (4 + i) * 1024);
    SBAR;
    WAITL0;
#pragma unroll
    for (int mi = 0; mi < 4; ++mi)
#pragma unroll
      for (int ni = 0; ni < 4; ++ni)
        acc[4 + mi][ni] = __builtin_amdgcn_mfma_f32_16x16x32_bf16(
            av[mi], bv0[ni], acc[4 + mi][ni], 0, 0, 0);
    WAITV(0);
    SBAR;
#pragma unroll
    for (int i = 0; i < 4; ++i) {
      av[i] = *(const bf16x8*)(bufp + 32768 + acore + i * 1024);
      bv1[i] = *(const bf16x8*)(bufp + 49152 + bcore + i * 1024);
    }
    WAITL0;
#pragma unroll
    for (int mi = 0; mi < 4; ++mi)
#pragma unroll
      for (int ni = 0; ni < 4; ++ni)
        acc[mi][ni] = __builtin_amdgcn_mfma_f32_16x16x32_bf16(
            av[mi], bv1[ni], acc[mi][ni], 0, 0, 0);
#pragma unroll
    for (int i = 0; i < 4; ++i)
      av[i] = *(const bf16x8*)(bufp + 32768 + acore + (4 + i) * 1024);
    WAITL0;
#pragma unroll
    for (int mi = 0; mi < 4; ++mi)
#pragma unroll
      for (int ni = 0; ni < 4; ++ni)
        acc[4 + mi][ni] = __builtin_amdgcn_mfma_f32_16x16x32_bf16(
            av[mi], bv1[ni], acc[4 + mi][ni], 0, 0, 0);
  }

  const float* nrmz = norm + z * normOffZ;
  float* Cf = C + z * cOffZ;
#pragma unroll
  for (int mi = 0; mi < 8; ++mi) {
    const int rbase = m0 + wm * 128 + mi * 16 + fq * 4;
    float nv[4];
#pragma unroll
    for (int j = 0; j < 4; ++j) nv[j] = nrmz[rbase + j];
#pragma unroll
    for (int ni = 0; ni < 4; ++ni) {
      const int c = n0 + wn * 64 + ni * 16 + fr;
#pragma unroll
      for (int j = 0; j < 4; ++j)
        Cf[(long long)(rbase + j) * ldc + c] = acc[mi][ni][j] / nv[j];
    }
  }
}

// ===== prep: 3x W-transpose + x->bf16 convert in one launch (z in 0..3) ===
__global__ __launch_bounds__(256) void prep_fused(
    const float* __restrict__ Wq, const float* __restrict__ Wk,
    const float* __restrict__ Wv, unsigned short* __restrict__ WT,
    const float4* __restrict__ x4, uint2* __restrict__ xb4) {
  __shared__ float tile[32][33];
  if (blockIdx.z < 3) {
    const float* W = blockIdx.z == 0 ? Wq : (blockIdx.z == 1 ? Wk : Wv);
    unsigned short* out = WT + (size_t)blockIdx.z * 1024 * 1024;
    const int tx = threadIdx.x & 31, ty = threadIdx.x >> 5;
    const int i0 = blockIdx.y * 32, o0 = blockIdx.x * 32;
#pragma unroll
    for (int s = 0; s < 32; s += 8)
      tile[ty + s][tx] = W[(long long)(i0 + ty + s) * 1024 + o0 + tx];
    __syncthreads();
#pragma unroll
    for (int s = 0; s < 32; s += 8)
      out[(long long)(o0 + ty + s) * 1024 + i0 + tx] = f2bf(tile[tx][ty + s]);
  } else {
    const int flat = blockIdx.y * 32 + blockIdx.x;  // 0..1023
    const int n4 = 4194304;                          // 16384*1024/4
    for (int i = flat * 256 + threadIdx.x; i < n4; i += 1024 * 256) {
      float4 v = x4[i];
      uint2 o;
      o.x = (unsigned)f2bf(v.x) | ((unsigned)f2bf(v.y) << 16);
      o.y = (unsigned)f2bf(v.z) | ((unsigned)f2bf(v.w) << 16);
      xb4[i] = o;
    }
  }
}

// K_sum[b][d] = sum_n KpT[d][b*4096 + n]  (full-chip 1024-block launch;
// R15 lesson: never shrink the parallelism of memory-bound work to save a
// launch - a launch costs ~2us, an under-parallelized 32MB scan costs 10x)
__global__ __launch_bounds__(256) void ksum_kernel(
    const unsigned short* __restrict__ KpT, float* __restrict__ Ksum) {
  const int gw = (blockIdx.x * 256 + threadIdx.x) >> 6;
  const int lane = threadIdx.x & 63;
  const int d = gw >> 2, b = gw & 3;
  const unsigned short* p = KpT + (long long)d * 16384 + b * 4096 + lane * 8;
  float s = 0.f;
#pragma unroll
  for (int it = 0; it < 8; ++it) {
    u16x8 v = *(const u16x8*)(p + it * 512);
#pragma unroll
    for (int j = 0; j < 8; ++j) s += bf2f(v[j]);
  }
#pragma unroll
  for (int o = 32; o > 0; o >>= 1) s += __shfl_down(s, o, 64);
  if (lane == 0) Ksum[b * 1024 + d] = s;
}

// ===== tail: KVt reduce (blocks <2048) + norm (blocks >=2048), one launch ==
__global__ __launch_bounds__(256) void tail_fused(
    const unsigned short* __restrict__ P, unsigned short* __restrict__ KVt,
    const unsigned short* __restrict__ Qp, const float* __restrict__ Ksum,
    float* __restrict__ nrm) {
  if (blockIdx.x < 2048) {
    const long long i = ((long long)blockIdx.x * 256 + threadIdx.x) * 8;
    const int b = (int)(i >> 20);
    const long long ed = i & ((1ll << 20) - 1);
    float s[8] = {0.f, 0.f, 0.f, 0.f, 0.f, 0.f, 0.f, 0.f};
#pragma unroll
    for (int ks = 0; ks < 4; ++ks) {
      u16x8 v = *(const u16x8*)(P + ((long long)(ks * 4 + b) << 20) + ed);
#pragma unroll
      for (int j = 0; j < 8; ++j) s[j] += bf2f(v[j]);
    }
    u16x8 o;
#pragma unroll
    for (int j = 0; j < 8; ++j) o[j] = f2bf(s[j]);
    *(u16x8*)(KVt + i) = o;
  } else {
    const int gw = ((blockIdx.x - 2048) * 256 + threadIdx.x) >> 6;
    const int lane = threadIdx.x & 63;
    const int b = gw >> 12;
    const unsigned short* q = Qp + (long long)gw * 1024 + lane * 8;
    const float* ks = Ksum + b * 1024 + lane * 8;
    float s = 0.f;
#pragma unroll
    for (int it = 0; it < 2; ++it) {
      u16x8 v = *(const u16x8*)(q + it * 512);
      float4 k0 = *(const float4*)(ks + it * 512);
      float4 k1 = *(const float4*)(ks + it * 512 + 4);
      s += bf2f(v[0]) * k0.x + bf2f(v[1]) * k0.y + bf2f(v[2]) * k0.z +
           bf2f(v[3]) * k0.w + bf2f(v[4]) * k1.x + bf2f(v[5]) * k1.y +
           bf2f(v[6]) * k1.z + bf2f(v[7]) * k1.w;
    }
#pragma unroll
    for (int o = 32; o > 0; o >>= 1) s += __shfl_down(s, o, 64);
    if (lane == 0) nrm[gw] = s + 1e-6f;
  }
}

extern "C" void kernel_launch(void* const* d_in, const int* in_sizes, int n_in,
                              void* d_out, int out_size, void* d_ws,
                              size_t ws_size, hipStream_t stream) {
  const float* x  = (const float*)d_in[0];
  const float* Wq = (const float*)d_in[1];
  const float* bq = (const float*)d_in[2];
  const float* Wk = (const float*)d_in[3];
  const float* bk = (const float*)d_in[4];
  const float* Wv = (const float*)d_in[5];
  const float* bv = (const float*)d_in[6];
  float* out = (float*)d_out;

  const size_t MN = 16384ull * 1024ull;
  char* w = (char*)d_ws;
  unsigned short* xb  = (unsigned short*)w;  w += MN * 2;
  unsigned short* WT  = (unsigned short*)w;  w += 3ull * 1024 * 1024 * 2;
  unsigned short* Qp  = (unsigned short*)w;  w += MN * 2;
  unsigned short* KVb = (unsigned short*)w;  w += 2 * MN * 2;
  unsigned short* KVt = (unsigned short*)w;  w += 4ull * 1024 * 1024 * 2;
  float* Ksum = (float*)w;  w += 4ull * 1024 * 4;
  float* nrm  = (float*)w;  w += 16384ull * 4;
  unsigned short* Pkv = xb;  // split-K partials alias dead xb
  unsigned short* KpT = KVb;
  unsigned short* VT  = KVb + MN;

  // 1) W transposes + x conversion (one launch)
  prep_fused<<<dim3(32, 32, 4), 256, 0, stream>>>(Wq, Wk, Wv, WT,
                                                  (const float4*)x, (uint2*)xb);
  // 2) Qp + merged KV projection (one 768-block launch; KVproj first)
  proj_fused<<<768, 1024, 0, stream>>>(xb, WT, Qp, KVb, bq, bk, bv);
  // 3) K_sum (full-chip)
  ksum_kernel<<<1024, 256, 0, stream>>>(KpT, Ksum);
  // 4) split-K KVt partials: z = ks*4+b
  gemm_splitk<<<dim3(4, 4, 16), 1024, 0, stream>>>(VT, KpT, Pkv);
  // 5) KVt reduce + norm (one launch)
  tail_fused<<<6144, 256, 0, stream>>>(Pkv, KVt, Qp, Ksum, nrm);
  // 6) numerator
  gemm_num<<<dim3(4, 16, 4), 512, 0, stream>>>(
      Qp, 4096ll * 1024, KVt, 1024 * 1024, out, 4096ll * 1024, nrm, 4096);
}